// Round 3
// baseline (126.113 us; speedup 1.0000x reference)
//
#include <hip/hip_runtime.h>

// GWD loss: pred(N,5) f32, target(N,5) f32, weight(N) f32 -> scalar mean.
// Round 3: no LDS. Vectorized-AoS: 4 rows/thread = 5x float4 per input,
// 11 independent loads in flight per thread, one group per thread (no loop).
// FUN='log', TAU=1.0, ALPHA=1.0, LOSS_WEIGHT=1.0.

__device__ __forceinline__ float gwd_row(const float* __restrict__ p,
                                         const float* __restrict__ t)
{
    const float px = p[0], py = p[1], pw = p[2], ph = p[3], pr = p[4];
    const float tx = t[0], ty = t[1], tw = t[2], th = t[3], tr = t[4];

    const float dx = px - tx;
    const float dy = py - ty;
    const float xy_dist = dx * dx + dy * dy;

    const float a2p = 0.25f * pw * pw;
    const float b2p = 0.25f * ph * ph;
    const float a2t = 0.25f * tw * tw;
    const float b2t = 0.25f * th * th;

    float whr = (a2p + b2p) + (a2t + b2t);

    float cp, sp, ct, st;
    __sincosf(pr, &sp, &cp);
    __sincosf(tr, &st, &ct);

    // Sigma = R diag(a2,b2) R^T
    const float Sp00 = cp * cp * a2p + sp * sp * b2p;
    const float Sp01 = cp * sp * (a2p - b2p);
    const float Sp11 = sp * sp * a2p + cp * cp * b2p;
    const float St00 = ct * ct * a2t + st * st * b2t;
    const float St01 = ct * st * (a2t - b2t);
    const float St11 = st * st * a2t + ct * ct * b2t;

    // tr(Sp^1/2 St Sp^1/2) = tr(Sp St); det(cross) = det(Sp)det(St) >= 0
    const float tr_cross  = Sp00 * St00 + 2.0f * Sp01 * St01 + Sp11 * St11;
    const float det_cross = (a2p * b2p) * (a2t * b2t);

    float sq = fmaxf(tr_cross + 2.0f * sqrtf(det_cross), 0.0f);
    whr = whr - 2.0f * sqrtf(sq);

    float distance = sqrtf(fmaxf(xy_dist + whr, 0.0f));   // ALPHA = 1

    const float prod = (pw * tw) * (ph * th);
    distance = distance / sqrtf(sqrtf(prod));             // (prod)^(-1/4)

    distance = log1pf(distance);                          // FUN = 'log'
    return 1.0f - 1.0f / (1.0f + distance);               // TAU = 1
}

__global__ __launch_bounds__(256) void gwd_loss_kernel(
    const float* __restrict__ pred,
    const float* __restrict__ target,
    const float* __restrict__ weight,
    float* __restrict__ out,
    int n)
{
    const float inv_n = 1.0f / (float)n;
    const int g  = blockIdx.x * 256 + threadIdx.x;   // group of 4 rows
    const int r0 = g * 4;
    float acc = 0.0f;

    if (r0 + 3 < n) {
        // ---- fast path: 5+5+1 independent float4 loads ----
        const float4* p4 = (const float4*)pred   + (size_t)g * 5;
        const float4* t4 = (const float4*)target + (size_t)g * 5;
        const float4  w4 = ((const float4*)weight)[g];

        float pbuf[20], tbuf[20];
        float4 P0 = p4[0], P1 = p4[1], P2 = p4[2], P3 = p4[3], P4 = p4[4];
        float4 T0 = t4[0], T1 = t4[1], T2 = t4[2], T3 = t4[3], T4 = t4[4];
        *(float4*)(pbuf +  0) = P0; *(float4*)(pbuf +  4) = P1;
        *(float4*)(pbuf +  8) = P2; *(float4*)(pbuf + 12) = P3;
        *(float4*)(pbuf + 16) = P4;
        *(float4*)(tbuf +  0) = T0; *(float4*)(tbuf +  4) = T1;
        *(float4*)(tbuf +  8) = T2; *(float4*)(tbuf + 12) = T3;
        *(float4*)(tbuf + 16) = T4;

        const float w[4] = { w4.x, w4.y, w4.z, w4.w };
        #pragma unroll
        for (int j = 0; j < 4; ++j)
            acc += gwd_row(&pbuf[j * 5], &tbuf[j * 5]) * w[j];
    } else {
        // ---- tail: per-row scalar (only the last partial group) ----
        for (int r = r0; r < n && r < r0 + 4; ++r) {
            float pb[5], tb[5];
            #pragma unroll
            for (int k = 0; k < 5; ++k) { pb[k] = pred[r * 5 + k]; tb[k] = target[r * 5 + k]; }
            acc += gwd_row(pb, tb) * weight[r];
        }
    }

    // ---- wave-64 -> block -> global reduction ----
    #pragma unroll
    for (int off = 32; off > 0; off >>= 1)
        acc += __shfl_down(acc, off, 64);

    __shared__ float wave_sums[4];
    const int lane = threadIdx.x & 63;
    const int wid  = threadIdx.x >> 6;
    if (lane == 0) wave_sums[wid] = acc;
    __syncthreads();

    if (threadIdx.x == 0) {
        const float s = (wave_sums[0] + wave_sums[1]) + (wave_sums[2] + wave_sums[3]);
        atomicAdd(out, s * inv_n);   // LOSS_WEIGHT = 1
    }
}

extern "C" void kernel_launch(void* const* d_in, const int* in_sizes, int n_in,
                              void* d_out, int out_size, void* d_ws, size_t ws_size,
                              hipStream_t stream) {
    const float* pred   = (const float*)d_in[0];
    const float* target = (const float*)d_in[1];
    const float* weight = (const float*)d_in[2];
    float* out = (float*)d_out;

    const int n = in_sizes[2];   // weight has N elements

    // harness poisons d_out with 0xAA before every timed launch
    hipMemsetAsync(out, 0, sizeof(float), stream);

    const int block  = 256;
    const int groups = (n + 3) / 4;                 // 4 rows per thread
    const int grid   = (groups + block - 1) / block; // 1954 for N=2e6: one shot
    gwd_loss_kernel<<<grid, block, 0, stream>>>(pred, target, weight, out, n);
}

// Round 4
// 125.241 us; speedup vs baseline: 1.0070x; 1.0070x over previous
//
#include <hip/hip_runtime.h>

// GWD loss: pred(N,5) f32, target(N,5) f32, weight(N) f32 -> scalar mean.
// Round 4: coalesced float4 staging (16 lines/instr) with FULLY UNROLLED
// register-buffered loads (10 in flight, no per-iter vmcnt(0) like R2),
// single LDS round-trip, 1024 rows/block single-shot.
// FUN='log', TAU=1.0, ALPHA=1.0, LOSS_WEIGHT=1.0.

#define CHUNK_ROWS 1024   // 1024 rows * 5 floats = 1280 float4 = 5 per thread

__device__ __forceinline__ float gwd_row(const float* __restrict__ p,
                                         const float* __restrict__ t)
{
    const float px = p[0], py = p[1], pw = p[2], ph = p[3], pr = p[4];
    const float tx = t[0], ty = t[1], tw = t[2], th = t[3], tr = t[4];

    const float dx = px - tx;
    const float dy = py - ty;
    const float xy_dist = dx * dx + dy * dy;

    const float a2p = 0.25f * pw * pw;
    const float b2p = 0.25f * ph * ph;
    const float a2t = 0.25f * tw * tw;
    const float b2t = 0.25f * th * th;

    float whr = (a2p + b2p) + (a2t + b2t);

    float cp, sp, ct, st;
    __sincosf(pr, &sp, &cp);
    __sincosf(tr, &st, &ct);

    // Sigma = R diag(a2,b2) R^T
    const float Sp00 = cp * cp * a2p + sp * sp * b2p;
    const float Sp01 = cp * sp * (a2p - b2p);
    const float Sp11 = sp * sp * a2p + cp * cp * b2p;
    const float St00 = ct * ct * a2t + st * st * b2t;
    const float St01 = ct * st * (a2t - b2t);
    const float St11 = st * st * a2t + ct * ct * b2t;

    // tr(Sp^1/2 St Sp^1/2) = tr(Sp St); det(cross) = det(Sp)det(St) >= 0
    const float tr_cross  = Sp00 * St00 + 2.0f * Sp01 * St01 + Sp11 * St11;
    const float det_cross = (a2p * b2p) * (a2t * b2t);

    float sq = fmaxf(tr_cross + 2.0f * sqrtf(det_cross), 0.0f);
    whr = whr - 2.0f * sqrtf(sq);

    float distance = sqrtf(fmaxf(xy_dist + whr, 0.0f));   // ALPHA = 1

    const float prod = (pw * tw) * (ph * th);
    distance = distance / sqrtf(sqrtf(prod));             // (prod)^(-1/4)

    distance = log1pf(distance);                          // FUN = 'log'
    return 1.0f - 1.0f / (1.0f + distance);               // TAU = 1
}

__global__ __launch_bounds__(256) void gwd_loss_kernel(
    const float* __restrict__ pred,
    const float* __restrict__ target,
    const float* __restrict__ weight,
    float* __restrict__ out,
    int n)
{
    // exactly 40960 B LDS -> 4 blocks/CU (reduction scratch reuses s_pred)
    __shared__ float s_pred[CHUNK_ROWS * 5];
    __shared__ float s_tgt [CHUNK_ROWS * 5];

    const float inv_n = 1.0f / (float)n;
    const int row0 = blockIdx.x * CHUNK_ROWS;
    const int tid  = threadIdx.x;
    float acc = 0.0f;

    if (row0 + CHUNK_ROWS <= n) {
        // ---- full chunk: coalesced staging, all loads issued before any wait ----
        const float4* p4 = (const float4*)(pred   + (size_t)row0 * 5);
        const float4* t4 = (const float4*)(target + (size_t)row0 * 5);

        float4 P[5], T[5];
        #pragma unroll
        for (int j = 0; j < 5; ++j) P[j] = p4[j * 256 + tid];
        #pragma unroll
        for (int j = 0; j < 5; ++j) T[j] = t4[j * 256 + tid];

        #pragma unroll
        for (int j = 0; j < 5; ++j) ((float4*)s_pred)[j * 256 + tid] = P[j];
        #pragma unroll
        for (int j = 0; j < 5; ++j) ((float4*)s_tgt )[j * 256 + tid] = T[j];
        __syncthreads();

        // ---- compute: rows tid, tid+256, ... (LDS lane-stride 5: conflict-free) ----
        #pragma unroll
        for (int rr = 0; rr < 4; ++rr) {
            const int r = tid + rr * 256;
            acc += gwd_row(&s_pred[r * 5], &s_tgt[r * 5]) * weight[row0 + r];
        }
    } else {
        // ---- tail block (at most one): direct scalar path ----
        for (int r = row0 + tid; r < n; r += 256) {
            float pb[5], tb[5];
            #pragma unroll
            for (int k = 0; k < 5; ++k) {
                pb[k] = pred  [(size_t)r * 5 + k];
                tb[k] = target[(size_t)r * 5 + k];
            }
            acc += gwd_row(pb, tb) * weight[r];
        }
    }

    // ---- wave-64 -> block -> global reduction (reuse s_pred as scratch) ----
    #pragma unroll
    for (int off = 32; off > 0; off >>= 1)
        acc += __shfl_down(acc, off, 64);

    __syncthreads();   // all LDS compute reads done before reuse
    const int lane = tid & 63;
    const int wid  = tid >> 6;
    if (lane == 0) s_pred[wid] = acc;
    __syncthreads();

    if (tid == 0) {
        const float s = (s_pred[0] + s_pred[1]) + (s_pred[2] + s_pred[3]);
        atomicAdd(out, s * inv_n);   // LOSS_WEIGHT = 1
    }
}

extern "C" void kernel_launch(void* const* d_in, const int* in_sizes, int n_in,
                              void* d_out, int out_size, void* d_ws, size_t ws_size,
                              hipStream_t stream) {
    const float* pred   = (const float*)d_in[0];
    const float* target = (const float*)d_in[1];
    const float* weight = (const float*)d_in[2];
    float* out = (float*)d_out;

    const int n = in_sizes[2];   // weight has N elements

    // harness poisons d_out with 0xAA before every timed launch
    hipMemsetAsync(out, 0, sizeof(float), stream);

    const int block = 256;
    const int grid  = (n + CHUNK_ROWS - 1) / CHUNK_ROWS;   // 1954 for N=2e6
    gwd_loss_kernel<<<grid, block, 0, stream>>>(pred, target, weight, out, n);
}